// Round 8
// baseline (1130.975 us; speedup 1.0000x reference)
//
#include <hip/hip_runtime.h>
#include <cstddef>

typedef unsigned short u16;
typedef float f32x4 __attribute__((ext_vector_type(4)));
typedef short bf16x8 __attribute__((ext_vector_type(8)));

// Problem dims
#define SDIM 256
#define CDIM 64
#define NDIM 2000
#define TDIM 500

#define MAT  (SDIM*SDIM)   // 65536
#define HMAT (CDIM*SDIM)   // 16384

// ---- workspace layout (float offsets into d_ws) ---- all PROBABILITY domain
#define OFF_POW    0u                        // [25][256][256] f32: pow[i] = Tm^(i+1)
#define OFF_R2     (OFF_POW + 25u*MAT)       // Tm^50
#define OFF_R4     (OFF_R2 + MAT)            // Tm^100
#define OFF_R8     (OFF_R4 + MAT)            // Tm^200
#define OFF_R16    (OFF_R8 + MAT)            // Tm^400
#define OFF_HEADS  (OFF_R16 + MAT)           // [20][64][256] f32: H_b = h0 @ Tm^25b
#define OFF_CW     (OFF_HEADS + 20u*HMAT)    // [500][64] f32 chain-weight probs
#define OFF_EPROB  (OFF_CW + 32000u)         // [256][2000] f32 emission probs
#define OFF_ET     (OFF_EPROB + 512000u)     // u16: E^T bf16 [2048 n][256 k]
#define OFF_PT     (OFF_ET + 262144u)        // u16: P^T bf16 [25][256 n][256 k]
#define OFF_HDB    (OFF_PT + 819200u)        // u16: heads bf16 [20][64][256]
#define OFF_HB     (OFF_HDB + 163840u)       // u16: hidden bf16 [500][64][256]
// end ~ 7.7M floats ~ 31 MB

// d_out layout: log_obs [500][2000] | log_obs_ [500][64][2000] | log_hidden [500][64][256]
#define OUT_OBSB  1000000u
#define OUT_HIDB  65000000u

#define TP 260   // padded LDS tile stride (floats); 260%32=4 -> conflict-free acc stores

__device__ __forceinline__ float waveMax(float v) {
#pragma unroll
  for (int o = 32; o >= 1; o >>= 1) v = fmaxf(v, __shfl_xor(v, o));
  return v;
}
__device__ __forceinline__ float waveSum(float v) {
#pragma unroll
  for (int o = 32; o >= 1; o >>= 1) v += __shfl_xor(v, o);
  return v;
}
__device__ __forceinline__ u16 f2b(float f) {
  union { float f; unsigned u; } x; x.f = f;
  return (u16)((x.u + 0x7fffu + ((x.u >> 16) & 1u)) >> 16);
}

// ---------------- prep: row softmax -> PROBABILITIES for all four inputs ----------------
__global__ __launch_bounds__(256) void prep_prob(
    const float* __restrict__ si, const float* __restrict__ cw,
    const float* __restrict__ em, const float* __restrict__ tm,
    const float* __restrict__ mask, float* __restrict__ ws) {
  int b = blockIdx.x;
  const float* src; const float* msk = nullptr; float* dst; int len;
  if (b < 64)       { src = si + b*SDIM;                 dst = ws + OFF_HEADS + b*SDIM; len = SDIM; }
  else if (b < 564) { int r = b - 64;  src = cw + r*64;  dst = ws + OFF_CW + r*64;      len = 64;   }
  else if (b < 820) { int r = b - 564; src = tm + (size_t)r*SDIM; dst = ws + OFF_POW + (size_t)r*SDIM; len = SDIM; }
  else              { int r = b - 820; src = em + (size_t)r*NDIM; dst = ws + OFF_EPROB + (size_t)r*NDIM; len = NDIM; msk = mask + (size_t)r*NDIM; }
  int tid = threadIdx.x;
  __shared__ float rA[4], rB[4];
  float m = -INFINITY;
  for (int i = tid; i < len; i += 256) {
    float v = src[i];
    if (msk) v += __logf(msk[i]);
    m = fmaxf(m, v);
  }
  m = waveMax(m);
  if ((tid & 63) == 0) rA[tid >> 6] = m;
  __syncthreads();
  m = fmaxf(fmaxf(rA[0], rA[1]), fmaxf(rA[2], rA[3]));
  float s = 0.f;
  for (int i = tid; i < len; i += 256) {
    float v = src[i];
    if (msk) v += __logf(msk[i]);
    s += __expf(v - m);
  }
  s = waveSum(s);
  if ((tid & 63) == 0) rB[tid >> 6] = s;
  __syncthreads();
  s = rB[0] + rB[1] + rB[2] + rB[3];
  float inv = 1.f / s;
  for (int i = tid; i < len; i += 256) {
    float v = src[i];
    if (msk) v += __logf(msk[i]);
    dst[i] = __expf(v - m) * inv;
  }
}

// ---------------- plain fp32 prob-domain GEMM tile (chain) ----------------
__device__ void gemm_tile(const float* __restrict__ A, const float* __restrict__ B,
                          float* __restrict__ C, int r0, int n0) {
  __shared__ float As[64][68];   // [k][m]
  __shared__ float Bs[64][68];   // [k][n]
  int tid = threadIdx.x;
  float acc[4][4] = {};
  int tm4 = (tid >> 4) << 2, tn4 = (tid & 15) << 2;
  for (int kc = 0; kc < 4; ++kc) {
    __syncthreads();
    {
      int rr = tid >> 2, p = tid & 3;
      const float* sA = A + (size_t)(r0 + rr)*SDIM + kc*64 + p*16;
#pragma unroll
      for (int i = 0; i < 16; ++i) As[p*16 + i][rr] = sA[i];
    }
    {
      int kk = tid >> 2, p = tid & 3;
      const float* sB = B + (size_t)(kc*64 + kk)*SDIM + n0 + p*16;
#pragma unroll
      for (int i = 0; i < 16; ++i) Bs[kk][p*16 + i] = sB[i];
    }
    __syncthreads();
#pragma unroll 8
    for (int k = 0; k < 64; ++k) {
      float4 av = *(const float4*)&As[k][tm4];
      float4 bv = *(const float4*)&Bs[k][tn4];
      float a[4] = {av.x, av.y, av.z, av.w};
      float bb[4] = {bv.x, bv.y, bv.z, bv.w};
#pragma unroll
      for (int i = 0; i < 4; ++i)
#pragma unroll
        for (int j = 0; j < 4; ++j) acc[i][j] += a[i]*bb[j];
    }
  }
#pragma unroll
  for (int i = 0; i < 4; ++i)
    *(float4*)&C[(size_t)(r0 + tm4 + i)*SDIM + n0 + tn4] =
        make_float4(acc[i][0], acc[i][1], acc[i][2], acc[i][3]);
}

struct Jobs {
  int n;
  unsigned aOff[12], bOff[12], cOff[12];
  int M[12];
};

__global__ __launch_bounds__(256) void gemm_kernel(float* __restrict__ ws, Jobs jobs) {
  int j = blockIdx.z;
  if (blockIdx.x * 64 >= jobs.M[j]) return;
  gemm_tile(ws + jobs.aOff[j], ws + jobs.bOff[j], ws + jobs.cOff[j],
            blockIdx.x * 64, blockIdx.y * 64);
}

// ---------------- coalesced tiled transpose fp32 -> bf16: dst[n][256] = src[k][n] ----------------
__global__ __launch_bounds__(256) void transpose_b16(
    const float* __restrict__ srcBase, int ldn, int nReal, unsigned srcZ,
    u16* __restrict__ dstBase, unsigned dstZ) {
  const float* src = srcBase + (size_t)blockIdx.z * srcZ;
  u16* dst = dstBase + (size_t)blockIdx.z * dstZ;
  int n0 = blockIdx.x * 64, k0 = blockIdx.y * 64;
  __shared__ float tile[64][65];   // [n_local][k_local]
  int tid = threadIdx.x;
  {
    int kk = tid >> 2, p = tid & 3;      // row k0+kk, 16 consecutive n
    const float* s = src + (size_t)(k0 + kk)*ldn + n0 + p*16;
#pragma unroll
    for (int i = 0; i < 16; ++i) {
      int n = n0 + p*16 + i;
      tile[p*16 + i][kk] = (n < nReal) ? s[i] : 0.f;
    }
  }
  __syncthreads();
  {
    int rr = tid >> 2, kq = (tid & 3) * 16;   // write n-row n0+rr, 16 k
    unsigned w[8];
#pragma unroll
    for (int i = 0; i < 8; ++i)
      w[i] = (unsigned)f2b(tile[rr][kq + 2*i]) | ((unsigned)f2b(tile[rr][kq + 2*i + 1]) << 16);
    uint4* d = (uint4*)(dst + (size_t)(n0 + rr)*256 + k0 + kq);
    d[0] = *(uint4*)&w[0];
    d[1] = *(uint4*)&w[4];
  }
}

// heads fp32 -> bf16
__global__ __launch_bounds__(256) void prep_headsb(float* __restrict__ ws_f) {
  int b = blockIdx.x, tid = threadIdx.x;
  const float* src = ws_f + OFF_HEADS + (size_t)b*HMAT;
  u16* dst = (u16*)(ws_f + OFF_HDB) + (size_t)b*HMAT;
  for (int i = tid; i < HMAT/2; i += 256) {
    float2 v = *(const float2*)(src + 2*i);
    ((unsigned*)dst)[i] = (unsigned)f2b(v.x) | ((unsigned)f2b(v.y) << 16);
  }
}

// ---------------- MFMA helpers (64x256 out, K=256, chunked K=64, XOR-swizzled LDS) ----------------
__device__ __forceinline__ void stageAB(int tid, const u16* __restrict__ gA,
                                        const u16* __restrict__ gB, int kc,
                                        char* ldsA, char* ldsB) {
#pragma unroll
  for (int p = 0; p < 2; ++p) {
    int row = p*32 + (tid >> 3), slot = tid & 7;
    uint4 v = *(const uint4*)((const char*)gA + (size_t)row*512 + kc*128 + slot*16);
    *(uint4*)(ldsA + row*128 + ((slot*16) ^ ((row & 7) << 4))) = v;
  }
#pragma unroll
  for (int p = 0; p < 8; ++p) {
    int row = p*32 + (tid >> 3), slot = tid & 7;
    uint4 v = *(const uint4*)((const char*)gB + (size_t)row*512 + kc*128 + slot*16);
    *(uint4*)(ldsB + row*128 + ((slot*16) ^ ((row & 7) << 4))) = v;
  }
}

__device__ __forceinline__ void mfma_block(int g16, int c16, int wid,
                                           const char* ldsA, const char* ldsB,
                                           f32x4 (&acc)[4][4]) {
#pragma unroll
  for (int ks = 0; ks < 2; ++ks) {
    bf16x8 af[4], bfr[4];
    int kb = ks*64 + g16*16;
#pragma unroll
    for (int mf = 0; mf < 4; ++mf) {
      int row = mf*16 + c16;
      af[mf] = *(const bf16x8*)(ldsA + row*128 + (kb ^ ((row & 7) << 4)));
    }
#pragma unroll
    for (int nf = 0; nf < 4; ++nf) {
      int n = wid*64 + nf*16 + c16;
      bfr[nf] = *(const bf16x8*)(ldsB + n*128 + (kb ^ ((n & 7) << 4)));
    }
#pragma unroll
    for (int mf = 0; mf < 4; ++mf)
#pragma unroll
      for (int nf = 0; nf < 4; ++nf)
        acc[mf][nf] = __builtin_amdgcn_mfma_f32_16x16x32_bf16(af[mf], bfr[nf], acc[mf][nf], 0, 0, 0);
  }
}

// fill: h_t = H_b @ P_j (prob domain); writes log_hidden (f32, coalesced NT) + hidden bf16
__global__ __launch_bounds__(256) void fill_mfma(float* __restrict__ ws_f, float* __restrict__ out) {
  int tt = blockIdx.x;
  int b = tt / 25, j = tt % 25;
  int tid = threadIdx.x;
  float* hid = out + OUT_HIDB + (size_t)tt*HMAT;
  u16* hb = (u16*)(ws_f + OFF_HB) + (size_t)tt*HMAT;
  if (j == 0) {
    const float* H = ws_f + OFF_HEADS + (size_t)b*HMAT;
    for (int i = tid; i < HMAT; i += 256) {
      float v = H[i];
      hid[i] = __logf(v);
      hb[i] = f2b(v);
    }
    return;
  }
  const u16* gA = (const u16*)(ws_f + OFF_HDB) + (size_t)b*HMAT;
  const u16* gB = (const u16*)(ws_f + OFF_PT) + (size_t)(j - 1)*MAT;
  __shared__ __align__(16) char smem[41600];
  char* ldsA = smem; char* ldsB = smem + 8192;
  int wid = tid >> 6, lane = tid & 63, g16 = lane >> 4, c16 = lane & 15;
  f32x4 acc[4][4];
#pragma unroll
  for (int mf = 0; mf < 4; ++mf)
#pragma unroll
    for (int nf = 0; nf < 4; ++nf) acc[mf][nf] = {0.f, 0.f, 0.f, 0.f};
  stageAB(tid, gA, gB, 0, ldsA, ldsB);
  __syncthreads();
  for (int kc = 0; kc < 4; ++kc) {
    mfma_block(g16, c16, wid, ldsA, ldsB, acc);
    __syncthreads();
    if (kc < 3) { stageAB(tid, gA, gB, kc + 1, ldsA, ldsB); __syncthreads(); }
  }
  // ---- restaged coalesced epilogue: two 32-row passes through LDS ----
  float* tile = (float*)smem;   // [32][TP]
#pragma unroll
  for (int p = 0; p < 2; ++p) {
#pragma unroll
    for (int mf = 2*p; mf < 2*p + 2; ++mf)
#pragma unroll
      for (int r = 0; r < 4; ++r) {
        int lrow = mf*16 + g16*4 + r - 32*p;
#pragma unroll
        for (int nf = 0; nf < 4; ++nf) {
          int n = wid*64 + nf*16 + c16;
          tile[lrow*TP + n] = acc[mf][nf][r];
        }
      }
    __syncthreads();
    {
      int lr = tid & 31, seg = (tid >> 5) * 32;
      int c = 32*p + lr;
      const float* s = &tile[lr*TP + seg];
      float* dF = hid + (size_t)c*256 + seg;
      u16* dB = hb + (size_t)c*256 + seg;
#pragma unroll
      for (int q = 0; q < 8; ++q) {
        f32x4 lg = {__logf(s[4*q]), __logf(s[4*q+1]), __logf(s[4*q+2]), __logf(s[4*q+3])};
        __builtin_nontemporal_store(lg, (f32x4*)(dF + 4*q));
      }
#pragma unroll
      for (int q = 0; q < 4; ++q) {
        unsigned w[4];
#pragma unroll
        for (int i = 0; i < 4; ++i)
          w[i] = (unsigned)f2b(s[8*q + 2*i]) | ((unsigned)f2b(s[8*q + 2*i + 1]) << 16);
        *(uint4*)(dB + 8*q) = *(uint4*)&w[0];
      }
    }
    __syncthreads();
  }
}

// emission: obs = hidden @ E (prob); coalesced NT log_obs_ writes + fused log_obs reduction
__global__ __launch_bounds__(256) void emission_mfma(const float* __restrict__ ws_f, float* __restrict__ out) {
  int tt = blockIdx.y, n0 = blockIdx.x * 256;
  int tid = threadIdx.x;
  const u16* gA = (const u16*)(ws_f + OFF_HB) + (size_t)tt*HMAT;
  const u16* gB = (const u16*)(ws_f + OFF_ET) + (size_t)n0*256;
  __shared__ __align__(16) char smem[41600];
  __shared__ float sCw[64];
  char* ldsA = smem; char* ldsB = smem + 8192;
  if (tid < 64) sCw[tid] = ws_f[OFF_CW + tt*64 + tid];
  int wid = tid >> 6, lane = tid & 63, g16 = lane >> 4, c16 = lane & 15;
  f32x4 acc[4][4];
#pragma unroll
  for (int mf = 0; mf < 4; ++mf)
#pragma unroll
    for (int nf = 0; nf < 4; ++nf) acc[mf][nf] = {0.f, 0.f, 0.f, 0.f};
  stageAB(tid, gA, gB, 0, ldsA, ldsB);
  __syncthreads();
  for (int kc = 0; kc < 4; ++kc) {
    mfma_block(g16, c16, wid, ldsA, ldsB, acc);
    __syncthreads();
    if (kc < 3) { stageAB(tid, gA, gB, kc + 1, ldsA, ldsB); __syncthreads(); }
  }
  // ---- fused log_obs reduction over c (register path) ----
  float s[4] = {0.f, 0.f, 0.f, 0.f};
  int nn[4];
#pragma unroll
  for (int nf = 0; nf < 4; ++nf) nn[nf] = n0 + wid*64 + nf*16 + c16;
#pragma unroll
  for (int mf = 0; mf < 4; ++mf)
#pragma unroll
    for (int r = 0; r < 4; ++r) {
      float wc = sCw[mf*16 + g16*4 + r];
#pragma unroll
      for (int nf = 0; nf < 4; ++nf) s[nf] += acc[mf][nf][r] * wc;
    }
#pragma unroll
  for (int nf = 0; nf < 4; ++nf) {
    s[nf] += __shfl_xor(s[nf], 16);
    s[nf] += __shfl_xor(s[nf], 32);
  }
  if (g16 == 0) {
#pragma unroll
    for (int nf = 0; nf < 4; ++nf)
      if (nn[nf] < NDIM) out[(size_t)tt*NDIM + nn[nf]] = __logf(s[nf]);
  }
  // ---- restaged coalesced log_obs_ writes: two 32-row passes ----
  float* obsb = out + OUT_OBSB + (size_t)tt*CDIM*NDIM;
  float* tile = (float*)smem;   // [32][TP]
#pragma unroll
  for (int p = 0; p < 2; ++p) {
    __syncthreads();
#pragma unroll
    for (int mf = 2*p; mf < 2*p + 2; ++mf)
#pragma unroll
      for (int r = 0; r < 4; ++r) {
        int lrow = mf*16 + g16*4 + r - 32*p;
#pragma unroll
        for (int nf = 0; nf < 4; ++nf) {
          int n = wid*64 + nf*16 + c16;
          tile[lrow*TP + n] = acc[mf][nf][r];
        }
      }
    __syncthreads();
    {
      int lr = tid & 31, seg = (tid >> 5) * 32;
      int c = 32*p + lr;
      const float* s2 = &tile[lr*TP + seg];
      int nbase = n0 + seg;
      float* d = obsb + (size_t)c*NDIM + nbase;
      if (nbase + 32 <= NDIM) {
#pragma unroll
        for (int q = 0; q < 8; ++q) {
          f32x4 v = {__logf(s2[4*q]), __logf(s2[4*q+1]), __logf(s2[4*q+2]), __logf(s2[4*q+3])};
          __builtin_nontemporal_store(v, (f32x4*)(d + 4*q));
        }
      } else {
        for (int i = 0; i < 32; ++i)
          if (nbase + i < NDIM) d[i] = __logf(s2[i]);
      }
    }
  }
}

extern "C" void kernel_launch(void* const* d_in, const int* in_sizes, int n_in,
                              void* d_out, int out_size, void* d_ws, size_t ws_size,
                              hipStream_t stream) {
  const float* si   = (const float*)d_in[0];
  const float* cw   = (const float*)d_in[1];
  const float* em   = (const float*)d_in[2];
  const float* tm   = (const float*)d_in[3];
  const float* mask = (const float*)d_in[4];
  float* out = (float*)d_out;
  float* ws  = (float*)d_ws;
  dim3 blk(256);

  prep_prob<<<dim3(1076), blk, 0, stream>>>(si, cw, em, tm, mask, ws);

  // E^T bf16 (independent of chain)
  transpose_b16<<<dim3(32, 4, 1), blk, 0, stream>>>(ws + OFF_EPROB, NDIM, NDIM, 0,
                                                    (u16*)(ws + OFF_ET), 0);

  auto powOff  = [](int j){ return (unsigned)(OFF_POW + (unsigned)j*MAT); };
  auto headOff = [](int b){ return (unsigned)(OFF_HEADS + (unsigned)b*HMAT); };
  Jobs s;

  // powers P_1..P_25 by doubling (pow[i] = Tm^(i+1); pow[0] from prep)
  s.n = 1; s.aOff[0]=powOff(0); s.bOff[0]=powOff(0); s.cOff[0]=powOff(1); s.M[0]=256;
  gemm_kernel<<<dim3(4,4,1), blk, 0, stream>>>(ws, s);
  s.n = 2;
  s.aOff[0]=powOff(1); s.bOff[0]=powOff(0); s.cOff[0]=powOff(2); s.M[0]=256;
  s.aOff[1]=powOff(1); s.bOff[1]=powOff(1); s.cOff[1]=powOff(3); s.M[1]=256;
  gemm_kernel<<<dim3(4,4,2), blk, 0, stream>>>(ws, s);
  s.n = 4;
  for (int i=0;i<4;++i){ s.aOff[i]=powOff(3); s.bOff[i]=powOff(i); s.cOff[i]=powOff(4+i); s.M[i]=256; }
  gemm_kernel<<<dim3(4,4,4), blk, 0, stream>>>(ws, s);
  s.n = 8;
  for (int i=0;i<8;++i){ s.aOff[i]=powOff(7); s.bOff[i]=powOff(i); s.cOff[i]=powOff(8+i); s.M[i]=256; }
  gemm_kernel<<<dim3(4,4,8), blk, 0, stream>>>(ws, s);
  s.n = 9;
  for (int i=0;i<9;++i){ s.aOff[i]=powOff(15); s.bOff[i]=powOff(i); s.cOff[i]=powOff(16+i); s.M[i]=256; }
  gemm_kernel<<<dim3(4,4,9), blk, 0, stream>>>(ws, s);

  // P^T bf16 for fill (needs all powers)
  transpose_b16<<<dim3(4, 4, 25), blk, 0, stream>>>(ws + OFF_POW, SDIM, SDIM, MAT,
                                                    (u16*)(ws + OFF_PT), MAT);

  // heads H_b = h0 @ Tm^25b by doubling; R powers piggyback
  s.n = 2;
  s.aOff[0]=headOff(0); s.bOff[0]=powOff(24); s.cOff[0]=headOff(1); s.M[0]=64;
  s.aOff[1]=powOff(24); s.bOff[1]=powOff(24); s.cOff[1]=OFF_R2;     s.M[1]=256;
  gemm_kernel<<<dim3(4,4,2), blk, 0, stream>>>(ws, s);
  s.n = 3;
  s.aOff[0]=headOff(0); s.bOff[0]=OFF_R2; s.cOff[0]=headOff(2); s.M[0]=64;
  s.aOff[1]=headOff(1); s.bOff[1]=OFF_R2; s.cOff[1]=headOff(3); s.M[1]=64;
  s.aOff[2]=OFF_R2;     s.bOff[2]=OFF_R2; s.cOff[2]=OFF_R4;     s.M[2]=256;
  gemm_kernel<<<dim3(4,4,3), blk, 0, stream>>>(ws, s);
  s.n = 5;
  for (int i=0;i<4;++i){ s.aOff[i]=headOff(i); s.bOff[i]=OFF_R4; s.cOff[i]=headOff(4+i); s.M[i]=64; }
  s.aOff[4]=OFF_R4; s.bOff[4]=OFF_R4; s.cOff[4]=OFF_R8; s.M[4]=256;
  gemm_kernel<<<dim3(4,4,5), blk, 0, stream>>>(ws, s);
  s.n = 9;
  for (int i=0;i<8;++i){ s.aOff[i]=headOff(i); s.bOff[i]=OFF_R8; s.cOff[i]=headOff(8+i); s.M[i]=64; }
  s.aOff[8]=OFF_R8; s.bOff[8]=OFF_R8; s.cOff[8]=OFF_R16; s.M[8]=256;
  gemm_kernel<<<dim3(4,4,9), blk, 0, stream>>>(ws, s);
  s.n = 4;
  for (int i=0;i<4;++i){ s.aOff[i]=headOff(i); s.bOff[i]=OFF_R16; s.cOff[i]=headOff(16+i); s.M[i]=64; }
  gemm_kernel<<<dim3(4,4,4), blk, 0, stream>>>(ws, s);

  // heads -> bf16
  prep_headsb<<<dim3(20), blk, 0, stream>>>(ws);

  // all 500 h_t via MFMA -> log_hidden + hidden bf16
  fill_mfma<<<dim3(500), blk, 0, stream>>>(ws, out);

  // emission MFMA + fused log_obs reduction
  emission_mfma<<<dim3(8,500), blk, 0, stream>>>(ws, out);
}

// Round 9
// 490.700 us; speedup vs baseline: 2.3048x; 2.3048x over previous
//
#include <hip/hip_runtime.h>
#include <cstddef>

typedef unsigned short u16;
typedef float f32x4 __attribute__((ext_vector_type(4)));
typedef short bf16x8 __attribute__((ext_vector_type(8)));

// Problem dims
#define SDIM 256
#define CDIM 64
#define NDIM 2000
#define TDIM 500

#define MAT  (SDIM*SDIM)   // 65536
#define HMAT (CDIM*SDIM)   // 16384

// ---- workspace layout (float offsets into d_ws) ---- all PROBABILITY domain
#define OFF_POW    0u                        // [25][256][256] f32: pow[i] = Tm^(i+1)
#define OFF_R2     (OFF_POW + 25u*MAT)       // Tm^50
#define OFF_R4     (OFF_R2 + MAT)            // Tm^100
#define OFF_R8     (OFF_R4 + MAT)            // Tm^200
#define OFF_R16    (OFF_R8 + MAT)            // Tm^400
#define OFF_HEADS  (OFF_R16 + MAT)           // [20][64][256] f32: H_b = h0 @ Tm^25b
#define OFF_CW     (OFF_HEADS + 20u*HMAT)    // [500][64] f32 chain-weight probs
#define OFF_EPROB  (OFF_CW + 32000u)         // [256][2000] f32 emission probs
#define OFF_ET     (OFF_EPROB + 512000u)     // u16: E^T bf16 [2048 n][256 k]
#define OFF_PT     (OFF_ET + 262144u)        // u16: P^T bf16 [25][256 n][256 k]
#define OFF_HDB    (OFF_PT + 819200u)        // u16: heads bf16 [20][64][256]
#define OFF_HB     (OFF_HDB + 163840u)       // u16: hidden bf16 [500][64][256]
// end ~ 7.7M floats ~ 31 MB

// d_out layout: log_obs [500][2000] | log_obs_ [500][64][2000] | log_hidden [500][64][256]
#define OUT_OBSB  1000000u
#define OUT_HIDB  65000000u

#define TP 260   // padded LDS tile stride (floats)

__device__ __forceinline__ float waveMax(float v) {
#pragma unroll
  for (int o = 32; o >= 1; o >>= 1) v = fmaxf(v, __shfl_xor(v, o));
  return v;
}
__device__ __forceinline__ float waveSum(float v) {
#pragma unroll
  for (int o = 32; o >= 1; o >>= 1) v += __shfl_xor(v, o);
  return v;
}
__device__ __forceinline__ u16 f2b(float f) {
  union { float f; unsigned u; } x; x.f = f;
  return (u16)((x.u + 0x7fffu + ((x.u >> 16) & 1u)) >> 16);
}

// ---------------- prep: row softmax -> PROBABILITIES for all four inputs ----------------
__global__ __launch_bounds__(256) void prep_prob(
    const float* __restrict__ si, const float* __restrict__ cw,
    const float* __restrict__ em, const float* __restrict__ tm,
    const float* __restrict__ mask, float* __restrict__ ws) {
  int b = blockIdx.x;
  const float* src; const float* msk = nullptr; float* dst; int len;
  if (b < 64)       { src = si + b*SDIM;                 dst = ws + OFF_HEADS + b*SDIM; len = SDIM; }
  else if (b < 564) { int r = b - 64;  src = cw + r*64;  dst = ws + OFF_CW + r*64;      len = 64;   }
  else if (b < 820) { int r = b - 564; src = tm + (size_t)r*SDIM; dst = ws + OFF_POW + (size_t)r*SDIM; len = SDIM; }
  else              { int r = b - 820; src = em + (size_t)r*NDIM; dst = ws + OFF_EPROB + (size_t)r*NDIM; len = NDIM; msk = mask + (size_t)r*NDIM; }
  int tid = threadIdx.x;
  __shared__ float rA[4], rB[4];
  float m = -INFINITY;
  for (int i = tid; i < len; i += 256) {
    float v = src[i];
    if (msk) v += __logf(msk[i]);
    m = fmaxf(m, v);
  }
  m = waveMax(m);
  if ((tid & 63) == 0) rA[tid >> 6] = m;
  __syncthreads();
  m = fmaxf(fmaxf(rA[0], rA[1]), fmaxf(rA[2], rA[3]));
  float s = 0.f;
  for (int i = tid; i < len; i += 256) {
    float v = src[i];
    if (msk) v += __logf(msk[i]);
    s += __expf(v - m);
  }
  s = waveSum(s);
  if ((tid & 63) == 0) rB[tid >> 6] = s;
  __syncthreads();
  s = rB[0] + rB[1] + rB[2] + rB[3];
  float inv = 1.f / s;
  for (int i = tid; i < len; i += 256) {
    float v = src[i];
    if (msk) v += __logf(msk[i]);
    dst[i] = __expf(v - m) * inv;
  }
}

// ---------------- plain fp32 prob-domain GEMM tile (chain) ----------------
__device__ void gemm_tile(const float* __restrict__ A, const float* __restrict__ B,
                          float* __restrict__ C, int r0, int n0) {
  __shared__ float As[64][68];   // [k][m]
  __shared__ float Bs[64][68];   // [k][n]
  int tid = threadIdx.x;
  float acc[4][4] = {};
  int tm4 = (tid >> 4) << 2, tn4 = (tid & 15) << 2;
  for (int kc = 0; kc < 4; ++kc) {
    __syncthreads();
    {
      int rr = tid >> 2, p = tid & 3;
      const float* sA = A + (size_t)(r0 + rr)*SDIM + kc*64 + p*16;
#pragma unroll
      for (int i = 0; i < 16; ++i) As[p*16 + i][rr] = sA[i];
    }
    {
      int kk = tid >> 2, p = tid & 3;
      const float* sB = B + (size_t)(kc*64 + kk)*SDIM + n0 + p*16;
#pragma unroll
      for (int i = 0; i < 16; ++i) Bs[kk][p*16 + i] = sB[i];
    }
    __syncthreads();
#pragma unroll 8
    for (int k = 0; k < 64; ++k) {
      float4 av = *(const float4*)&As[k][tm4];
      float4 bv = *(const float4*)&Bs[k][tn4];
      float a[4] = {av.x, av.y, av.z, av.w};
      float bb[4] = {bv.x, bv.y, bv.z, bv.w};
#pragma unroll
      for (int i = 0; i < 4; ++i)
#pragma unroll
        for (int j = 0; j < 4; ++j) acc[i][j] += a[i]*bb[j];
    }
  }
#pragma unroll
  for (int i = 0; i < 4; ++i)
    *(float4*)&C[(size_t)(r0 + tm4 + i)*SDIM + n0 + tn4] =
        make_float4(acc[i][0], acc[i][1], acc[i][2], acc[i][3]);
}

struct Jobs {
  int n;
  unsigned aOff[12], bOff[12], cOff[12];
  int M[12];
};

__global__ __launch_bounds__(256) void gemm_kernel(float* __restrict__ ws, Jobs jobs) {
  int j = blockIdx.z;
  if (blockIdx.x * 64 >= jobs.M[j]) return;
  gemm_tile(ws + jobs.aOff[j], ws + jobs.bOff[j], ws + jobs.cOff[j],
            blockIdx.x * 64, blockIdx.y * 64);
}

// ---------------- coalesced tiled transpose fp32 -> bf16: dst[n][256] = src[k][n] ----------------
__global__ __launch_bounds__(256) void transpose_b16(
    const float* __restrict__ srcBase, int ldn, int nReal, unsigned srcZ,
    u16* __restrict__ dstBase, unsigned dstZ) {
  const float* src = srcBase + (size_t)blockIdx.z * srcZ;
  u16* dst = dstBase + (size_t)blockIdx.z * dstZ;
  int n0 = blockIdx.x * 64, k0 = blockIdx.y * 64;
  __shared__ float tile[64][65];   // [n_local][k_local]
  int tid = threadIdx.x;
  {
    int kk = tid >> 2, p = tid & 3;      // row k0+kk, 16 consecutive n
    const float* s = src + (size_t)(k0 + kk)*ldn + n0 + p*16;
#pragma unroll
    for (int i = 0; i < 16; ++i) {
      int n = n0 + p*16 + i;
      tile[p*16 + i][kk] = (n < nReal) ? s[i] : 0.f;
    }
  }
  __syncthreads();
  {
    int rr = tid >> 2, kq = (tid & 3) * 16;   // write n-row n0+rr, 16 k
    unsigned w[8];
#pragma unroll
    for (int i = 0; i < 8; ++i)
      w[i] = (unsigned)f2b(tile[rr][kq + 2*i]) | ((unsigned)f2b(tile[rr][kq + 2*i + 1]) << 16);
    uint4* d = (uint4*)(dst + (size_t)(n0 + rr)*256 + k0 + kq);
    d[0] = *(uint4*)&w[0];
    d[1] = *(uint4*)&w[4];
  }
}

// heads fp32 -> bf16
__global__ __launch_bounds__(256) void prep_headsb(float* __restrict__ ws_f) {
  int b = blockIdx.x, tid = threadIdx.x;
  const float* src = ws_f + OFF_HEADS + (size_t)b*HMAT;
  u16* dst = (u16*)(ws_f + OFF_HDB) + (size_t)b*HMAT;
  for (int i = tid; i < HMAT/2; i += 256) {
    float2 v = *(const float2*)(src + 2*i);
    ((unsigned*)dst)[i] = (unsigned)f2b(v.x) | ((unsigned)f2b(v.y) << 16);
  }
}

// ---------------- MFMA helpers (64x256 out, K=256, chunked K=64, XOR-swizzled LDS) ----------------
__device__ __forceinline__ void stageAB(int tid, const u16* __restrict__ gA,
                                        const u16* __restrict__ gB, int kc,
                                        char* ldsA, char* ldsB) {
#pragma unroll
  for (int p = 0; p < 2; ++p) {
    int row = p*32 + (tid >> 3), slot = tid & 7;
    uint4 v = *(const uint4*)((const char*)gA + (size_t)row*512 + kc*128 + slot*16);
    *(uint4*)(ldsA + row*128 + ((slot*16) ^ ((row & 7) << 4))) = v;
  }
#pragma unroll
  for (int p = 0; p < 8; ++p) {
    int row = p*32 + (tid >> 3), slot = tid & 7;
    uint4 v = *(const uint4*)((const char*)gB + (size_t)row*512 + kc*128 + slot*16);
    *(uint4*)(ldsB + row*128 + ((slot*16) ^ ((row & 7) << 4))) = v;
  }
}

__device__ __forceinline__ void mfma_block(int g16, int c16, int wid,
                                           const char* ldsA, const char* ldsB,
                                           f32x4 (&acc)[4][4]) {
#pragma unroll
  for (int ks = 0; ks < 2; ++ks) {
    bf16x8 af[4], bfr[4];
    int kb = ks*64 + g16*16;
#pragma unroll
    for (int mf = 0; mf < 4; ++mf) {
      int row = mf*16 + c16;
      af[mf] = *(const bf16x8*)(ldsA + row*128 + (kb ^ ((row & 7) << 4)));
    }
#pragma unroll
    for (int nf = 0; nf < 4; ++nf) {
      int n = wid*64 + nf*16 + c16;
      bfr[nf] = *(const bf16x8*)(ldsB + n*128 + (kb ^ ((n & 7) << 4)));
    }
#pragma unroll
    for (int mf = 0; mf < 4; ++mf)
#pragma unroll
      for (int nf = 0; nf < 4; ++nf)
        acc[mf][nf] = __builtin_amdgcn_mfma_f32_16x16x32_bf16(af[mf], bfr[nf], acc[mf][nf], 0, 0, 0);
  }
}

// fill: h_t = H_b @ P_j (prob domain); writes log_hidden (f32, wave-contiguous NT) + hidden bf16
__global__ __launch_bounds__(256) void fill_mfma(float* __restrict__ ws_f, float* __restrict__ out) {
  int tt = blockIdx.x;
  int b = tt / 25, j = tt % 25;
  int tid = threadIdx.x;
  float* hid = out + OUT_HIDB + (size_t)tt*HMAT;
  u16* hb = (u16*)(ws_f + OFF_HB) + (size_t)tt*HMAT;
  if (j == 0) {
    const float* H = ws_f + OFF_HEADS + (size_t)b*HMAT;
    for (int i = tid; i < HMAT; i += 256) {
      float v = H[i];
      hid[i] = __logf(v);
      hb[i] = f2b(v);
    }
    return;
  }
  const u16* gA = (const u16*)(ws_f + OFF_HDB) + (size_t)b*HMAT;
  const u16* gB = (const u16*)(ws_f + OFF_PT) + (size_t)(j - 1)*MAT;
  __shared__ __align__(16) char smem[41600];
  char* ldsA = smem; char* ldsB = smem + 8192;
  int wid = tid >> 6, lane = tid & 63, g16 = lane >> 4, c16 = lane & 15;
  f32x4 acc[4][4];
#pragma unroll
  for (int mf = 0; mf < 4; ++mf)
#pragma unroll
    for (int nf = 0; nf < 4; ++nf) acc[mf][nf] = {0.f, 0.f, 0.f, 0.f};
  stageAB(tid, gA, gB, 0, ldsA, ldsB);
  __syncthreads();
  for (int kc = 0; kc < 4; ++kc) {
    mfma_block(g16, c16, wid, ldsA, ldsB, acc);
    __syncthreads();
    if (kc < 3) { stageAB(tid, gA, gB, kc + 1, ldsA, ldsB); __syncthreads(); }
  }
  // ---- restaged epilogue: wave-row-contiguous stores (1 KB f32 / 512 B bf16 per wave-instr) ----
  float* tile = (float*)smem;   // [32][TP]
#pragma unroll
  for (int p = 0; p < 2; ++p) {
    if (p) __syncthreads();
#pragma unroll
    for (int mf = 2*p; mf < 2*p + 2; ++mf)
#pragma unroll
      for (int r = 0; r < 4; ++r) {
        int lrow = mf*16 + g16*4 + r - 32*p;
#pragma unroll
        for (int nf = 0; nf < 4; ++nf) {
          int n = wid*64 + nf*16 + c16;
          tile[lrow*TP + n] = acc[mf][nf][r];
        }
      }
    __syncthreads();
#pragma unroll
    for (int r8 = 0; r8 < 8; ++r8) {
      int row = wid*8 + r8;          // wave handles 8 rows; lanes span one full row
      int c = 32*p + row;
      f32x4 v = *(const f32x4*)&tile[row*TP + lane*4];
      f32x4 lg = {__logf(v[0]), __logf(v[1]), __logf(v[2]), __logf(v[3])};
      __builtin_nontemporal_store(lg, (f32x4*)(hid + (size_t)c*256 + lane*4));
      uint2 w;
      w.x = (unsigned)f2b(v[0]) | ((unsigned)f2b(v[1]) << 16);
      w.y = (unsigned)f2b(v[2]) | ((unsigned)f2b(v[3]) << 16);
      *(uint2*)(hb + (size_t)c*256 + lane*4) = w;   // hb is re-read -> normal store
    }
  }
}

// emission: obs = hidden @ E (prob); wave-row-contiguous NT log_obs_ writes + fused log_obs reduction
__global__ __launch_bounds__(256) void emission_mfma(const float* __restrict__ ws_f, float* __restrict__ out) {
  int tt = blockIdx.y, n0 = blockIdx.x * 256;
  int tid = threadIdx.x;
  const u16* gA = (const u16*)(ws_f + OFF_HB) + (size_t)tt*HMAT;
  const u16* gB = (const u16*)(ws_f + OFF_ET) + (size_t)n0*256;
  __shared__ __align__(16) char smem[41600];
  __shared__ float sCw[64];
  char* ldsA = smem; char* ldsB = smem + 8192;
  if (tid < 64) sCw[tid] = ws_f[OFF_CW + tt*64 + tid];
  int wid = tid >> 6, lane = tid & 63, g16 = lane >> 4, c16 = lane & 15;
  f32x4 acc[4][4];
#pragma unroll
  for (int mf = 0; mf < 4; ++mf)
#pragma unroll
    for (int nf = 0; nf < 4; ++nf) acc[mf][nf] = {0.f, 0.f, 0.f, 0.f};
  stageAB(tid, gA, gB, 0, ldsA, ldsB);
  __syncthreads();
  for (int kc = 0; kc < 4; ++kc) {
    mfma_block(g16, c16, wid, ldsA, ldsB, acc);
    __syncthreads();
    if (kc < 3) { stageAB(tid, gA, gB, kc + 1, ldsA, ldsB); __syncthreads(); }
  }
  // ---- fused log_obs reduction over c (register path) ----
  float s[4] = {0.f, 0.f, 0.f, 0.f};
  int nn[4];
#pragma unroll
  for (int nf = 0; nf < 4; ++nf) nn[nf] = n0 + wid*64 + nf*16 + c16;
#pragma unroll
  for (int mf = 0; mf < 4; ++mf)
#pragma unroll
    for (int r = 0; r < 4; ++r) {
      float wc = sCw[mf*16 + g16*4 + r];
#pragma unroll
      for (int nf = 0; nf < 4; ++nf) s[nf] += acc[mf][nf][r] * wc;
    }
#pragma unroll
  for (int nf = 0; nf < 4; ++nf) {
    s[nf] += __shfl_xor(s[nf], 16);
    s[nf] += __shfl_xor(s[nf], 32);
  }
  if (g16 == 0) {
#pragma unroll
    for (int nf = 0; nf < 4; ++nf)
      if (nn[nf] < NDIM) out[(size_t)tt*NDIM + nn[nf]] = __logf(s[nf]);
  }
  // ---- restaged log_obs_ writes: wave-row-contiguous NT (1 KB per wave-instr) ----
  float* obsb = out + OUT_OBSB + (size_t)tt*CDIM*NDIM;
  float* tile = (float*)smem;   // [32][TP]
  bool okc = (n0 + (lane + 1)*4 <= NDIM);   // cols are 4-aligned: fully in or fully out
#pragma unroll
  for (int p = 0; p < 2; ++p) {
    __syncthreads();
#pragma unroll
    for (int mf = 2*p; mf < 2*p + 2; ++mf)
#pragma unroll
      for (int r = 0; r < 4; ++r) {
        int lrow = mf*16 + g16*4 + r - 32*p;
#pragma unroll
        for (int nf = 0; nf < 4; ++nf) {
          int n = wid*64 + nf*16 + c16;
          tile[lrow*TP + n] = acc[mf][nf][r];
        }
      }
    __syncthreads();
#pragma unroll
    for (int r8 = 0; r8 < 8; ++r8) {
      int row = wid*8 + r8;          // wave handles 8 rows; lanes span one full row
      int c = 32*p + row;
      if (okc) {
        f32x4 v = *(const f32x4*)&tile[row*TP + lane*4];
        f32x4 lg = {__logf(v[0]), __logf(v[1]), __logf(v[2]), __logf(v[3])};
        __builtin_nontemporal_store(lg, (f32x4*)(obsb + (size_t)c*NDIM + n0 + lane*4));
      }
    }
  }
}

extern "C" void kernel_launch(void* const* d_in, const int* in_sizes, int n_in,
                              void* d_out, int out_size, void* d_ws, size_t ws_size,
                              hipStream_t stream) {
  const float* si   = (const float*)d_in[0];
  const float* cw   = (const float*)d_in[1];
  const float* em   = (const float*)d_in[2];
  const float* tm   = (const float*)d_in[3];
  const float* mask = (const float*)d_in[4];
  float* out = (float*)d_out;
  float* ws  = (float*)d_ws;
  dim3 blk(256);

  prep_prob<<<dim3(1076), blk, 0, stream>>>(si, cw, em, tm, mask, ws);

  // E^T bf16 (independent of chain)
  transpose_b16<<<dim3(32, 4, 1), blk, 0, stream>>>(ws + OFF_EPROB, NDIM, NDIM, 0,
                                                    (u16*)(ws + OFF_ET), 0);

  auto powOff  = [](int j){ return (unsigned)(OFF_POW + (unsigned)j*MAT); };
  auto headOff = [](int b){ return (unsigned)(OFF_HEADS + (unsigned)b*HMAT); };
  Jobs s;

  // powers P_1..P_25 by doubling (pow[i] = Tm^(i+1); pow[0] from prep)
  s.n = 1; s.aOff[0]=powOff(0); s.bOff[0]=powOff(0); s.cOff[0]=powOff(1); s.M[0]=256;
  gemm_kernel<<<dim3(4,4,1), blk, 0, stream>>>(ws, s);
  s.n = 2;
  s.aOff[0]=powOff(1); s.bOff[0]=powOff(0); s.cOff[0]=powOff(2); s.M[0]=256;
  s.aOff[1]=powOff(1); s.bOff[1]=powOff(1); s.cOff[1]=powOff(3); s.M[1]=256;
  gemm_kernel<<<dim3(4,4,2), blk, 0, stream>>>(ws, s);
  s.n = 4;
  for (int i=0;i<4;++i){ s.aOff[i]=powOff(3); s.bOff[i]=powOff(i); s.cOff[i]=powOff(4+i); s.M[i]=256; }
  gemm_kernel<<<dim3(4,4,4), blk, 0, stream>>>(ws, s);
  s.n = 8;
  for (int i=0;i<8;++i){ s.aOff[i]=powOff(7); s.bOff[i]=powOff(i); s.cOff[i]=powOff(8+i); s.M[i]=256; }
  gemm_kernel<<<dim3(4,4,8), blk, 0, stream>>>(ws, s);
  s.n = 9;
  for (int i=0;i<9;++i){ s.aOff[i]=powOff(15); s.bOff[i]=powOff(i); s.cOff[i]=powOff(16+i); s.M[i]=256; }
  gemm_kernel<<<dim3(4,4,9), blk, 0, stream>>>(ws, s);

  // P^T bf16 for fill (needs all powers)
  transpose_b16<<<dim3(4, 4, 25), blk, 0, stream>>>(ws + OFF_POW, SDIM, SDIM, MAT,
                                                    (u16*)(ws + OFF_PT), MAT);

  // heads H_b = h0 @ Tm^25b by doubling; R powers piggyback
  s.n = 2;
  s.aOff[0]=headOff(0); s.bOff[0]=powOff(24); s.cOff[0]=headOff(1); s.M[0]=64;
  s.aOff[1]=powOff(24); s.bOff[1]=powOff(24); s.cOff[1]=OFF_R2;     s.M[1]=256;
  gemm_kernel<<<dim3(4,4,2), blk, 0, stream>>>(ws, s);
  s.n = 3;
  s.aOff[0]=headOff(0); s.bOff[0]=OFF_R2; s.cOff[0]=headOff(2); s.M[0]=64;
  s.aOff[1]=headOff(1); s.bOff[1]=OFF_R2; s.cOff[1]=headOff(3); s.M[1]=64;
  s.aOff[2]=OFF_R2;     s.bOff[2]=OFF_R2; s.cOff[2]=OFF_R4;     s.M[2]=256;
  gemm_kernel<<<dim3(4,4,3), blk, 0, stream>>>(ws, s);
  s.n = 5;
  for (int i=0;i<4;++i){ s.aOff[i]=headOff(i); s.bOff[i]=OFF_R4; s.cOff[i]=headOff(4+i); s.M[i]=64; }
  s.aOff[4]=OFF_R4; s.bOff[4]=OFF_R4; s.cOff[4]=OFF_R8; s.M[4]=256;
  gemm_kernel<<<dim3(4,4,5), blk, 0, stream>>>(ws, s);
  s.n = 9;
  for (int i=0;i<8;++i){ s.aOff[i]=headOff(i); s.bOff[i]=OFF_R8; s.cOff[i]=headOff(8+i); s.M[i]=64; }
  s.aOff[8]=OFF_R8; s.bOff[8]=OFF_R8; s.cOff[8]=OFF_R16; s.M[8]=256;
  gemm_kernel<<<dim3(4,4,9), blk, 0, stream>>>(ws, s);
  s.n = 4;
  for (int i=0;i<4;++i){ s.aOff[i]=headOff(i); s.bOff[i]=OFF_R16; s.cOff[i]=headOff(16+i); s.M[i]=64; }
  gemm_kernel<<<dim3(4,4,4), blk, 0, stream>>>(ws, s);

  // heads -> bf16
  prep_headsb<<<dim3(20), blk, 0, stream>>>(ws);

  // all 500 h_t via MFMA -> log_hidden + hidden bf16
  fill_mfma<<<dim3(500), blk, 0, stream>>>(ws, out);

  // emission MFMA + fused log_obs reduction
  emission_mfma<<<dim3(8,500), blk, 0, stream>>>(ws, out);
}